// Round 13
// baseline (663.183 us; speedup 1.0000x reference)
//
#include <hip/hip_runtime.h>
#include <hip/hip_bf16.h>
#include <math.h>

typedef float f32x4 __attribute__((ext_vector_type(4)));
typedef __bf16 bf16x8 __attribute__((ext_vector_type(8)));
typedef unsigned short u16x8 __attribute__((ext_vector_type(8)));
typedef unsigned short u16x4 __attribute__((ext_vector_type(4)));

__device__ __forceinline__ float bf2f(unsigned short u) {
    unsigned int x = ((unsigned int)u) << 16;
    float f; __builtin_memcpy(&f, &x, 4); return f;
}
__device__ __forceinline__ unsigned short f2bf(float f) {
    unsigned int x; __builtin_memcpy(&x, &f, 4);
    unsigned int r = x + 0x7fffu + ((x >> 16) & 1u);
    return (unsigned short)(r >> 16);
}
// tanh-form GELU via hardware exp/rcp (~8 VALU ops vs ~40 for erff).
__device__ __forceinline__ float gelu_fast(float v) {
    float z2 = v * (1.5957691216f + 0.0713548162f * v * v);
    float e  = __expf(z2);
    float t  = 1.0f - 2.0f * __builtin_amdgcn_rcpf(1.0f + e);
    return 0.5f * v * (1.0f + t);
}
// async global -> LDS, 16 bytes per lane (global_load_lds_dwordx4)
__device__ __forceinline__ void gload_lds16(const unsigned short* g, unsigned short* l) {
    __builtin_amdgcn_global_load_lds(
        (const __attribute__((address_space(1))) unsigned int*)g,
        (__attribute__((address_space(3))) unsigned int*)l, 16, 0, 0);
}

// ---------------------------------------------------------------------------
// Weight transpose: fp32 [K][N] -> bf16 [N][K]
// ---------------------------------------------------------------------------
__global__ __launch_bounds__(256) void transpose_w(
    const float* __restrict__ in, unsigned short* __restrict__ out, int K, int N)
{
    __shared__ unsigned short tile[64][72];
    int nbn = N >> 6;
    int tk = (blockIdx.x / nbn) << 6;
    int tn = (blockIdx.x % nbn) << 6;
    int t = threadIdx.x;
    int r = t >> 2, c0 = (t & 3) * 16;
    #pragma unroll
    for (int i = 0; i < 16; i += 4) {
        float4 f = *(const float4*)(in + (size_t)(tk + r) * N + tn + c0 + i);
        tile[r][c0 + i + 0] = f2bf(f.x);
        tile[r][c0 + i + 1] = f2bf(f.y);
        tile[r][c0 + i + 2] = f2bf(f.z);
        tile[r][c0 + i + 3] = f2bf(f.w);
    }
    __syncthreads();
    u16x8 o0, o1;
    #pragma unroll
    for (int i = 0; i < 8; i++) { o0[i] = tile[c0 + i][r]; o1[i] = tile[c0 + 8 + i][r]; }
    *(u16x8*)(out + (size_t)(tn + r) * K + tk + c0)     = o0;
    *(u16x8*)(out + (size_t)(tn + r) * K + tk + c0 + 8) = o1;
}

// ---------------------------------------------------------------------------
// ksum[b*1024 + hm] = sum over l in [0,2048) of kpT[hm][b*2048 + l]
// kpT layout: [1024 features][16384 l-global]
// ---------------------------------------------------------------------------
__global__ __launch_bounds__(256) void ksum_kernel(
    const unsigned short* __restrict__ kpT, float* __restrict__ ksum)
{
    int idx = blockIdx.x * 4 + (threadIdx.x >> 6);   // 0..8191
    int lane = threadIdx.x & 63;
    int b = idx >> 10, hm = idx & 1023;
    const unsigned short* src = kpT + (size_t)hm * 16384 + b * 2048;
    float s = 0.f;
    #pragma unroll
    for (int g = 0; g < 4; g++) {
        u16x8 v = *(const u16x8*)(src + g * 512 + lane * 8);
        #pragma unroll
        for (int q = 0; q < 8; q++) s += bf2f(v[q]);
    }
    #pragma unroll
    for (int o = 32; o > 0; o >>= 1) s += __shfl_down(s, o);
    if (lane == 0) ksum[idx] = s;
}

// ---------------------------------------------------------------------------
// kvs partial GEMM: pbuf[sp][bh][d][m] = sum_{l in sp-chunk} vT[d][l]*kpT[m][l]
// vT/kpT layout: [1024 features][16384 l]; block (bh, sp) covers 512 l's.
// ---------------------------------------------------------------------------
__global__ __launch_bounds__(256) void kvs_mfma(
    const unsigned short* __restrict__ vT, const unsigned short* __restrict__ kpT,
    float* __restrict__ pbuf)
{
    int blk = blockIdx.x;
    int bh = blk >> 2, sp = blk & 3;
    int b = bh >> 4, h = bh & 15;
    const unsigned short* Abase = vT  + (size_t)(h * 64) * 16384 + b * 2048 + sp * 512;
    const unsigned short* Bbase = kpT + (size_t)(h * 64) * 16384 + b * 2048 + sp * 512;
    __shared__ unsigned short Al[64 * 64];
    __shared__ unsigned short Bl[64 * 64];
    int t = threadIdx.x;
    int lane = t & 63, wid = t >> 6;
    int l15 = lane & 15, l4 = lane >> 4;
    int wr = wid >> 1, wc = wid & 1;
    f32x4 acc[2][2] = {};
    for (int k0 = 0; k0 < 512; k0 += 64) {
        #pragma unroll
        for (int i = 0; i < 2; i++) {
            int chunk = i * 256 + t;
            int row = chunk >> 3, c = (chunk & 7) * 8;
            u16x8 av = *(const u16x8*)(Abase + (size_t)row * 16384 + k0 + c);
            u16x8 bv = *(const u16x8*)(Bbase + (size_t)row * 16384 + k0 + c);
            int off = (row * 128 + c * 2) ^ ((row & 7) << 4);
            *(u16x8*)((char*)Al + off) = av;
            *(u16x8*)((char*)Bl + off) = bv;
        }
        __syncthreads();
        #pragma unroll
        for (int kh = 0; kh < 2; kh++) {
            bf16x8 af[2], bf[2];
            #pragma unroll
            for (int mi = 0; mi < 2; mi++) {
                int row = wr * 32 + mi * 16 + l15;
                int off = (row * 128 + (kh * 32 + l4 * 8) * 2) ^ ((row & 7) << 4);
                af[mi] = *(const bf16x8*)((const char*)Al + off);
            }
            #pragma unroll
            for (int ni = 0; ni < 2; ni++) {
                int row = wc * 32 + ni * 16 + l15;
                int off = (row * 128 + (kh * 32 + l4 * 8) * 2) ^ ((row & 7) << 4);
                bf[ni] = *(const bf16x8*)((const char*)Bl + off);
            }
            #pragma unroll
            for (int mi = 0; mi < 2; mi++)
                #pragma unroll
                for (int ni = 0; ni < 2; ni++)
                    acc[mi][ni] = __builtin_amdgcn_mfma_f32_16x16x32_bf16(af[mi], bf[ni], acc[mi][ni], 0, 0, 0);
        }
        __syncthreads();
    }
    float* pb = pbuf + ((size_t)sp * 128 + bh) * 4096;
    #pragma unroll
    for (int mi = 0; mi < 2; mi++)
        #pragma unroll
        for (int ni = 0; ni < 2; ni++)
            #pragma unroll
            for (int j = 0; j < 4; j++) {
                int d = wr * 32 + mi * 16 + l4 * 4 + j;
                int m = wc * 32 + ni * 16 + l15;
                pb[d * 64 + m] = acc[mi][ni][j];
            }
}

// ---------------------------------------------------------------------------
// kvsT[i] = sum_sp pbuf[sp][i]
// ---------------------------------------------------------------------------
__global__ __launch_bounds__(256) void reduce4(
    const float* __restrict__ pbuf, float* __restrict__ out)
{
    int i = blockIdx.x * 256 + threadIdx.x;
    float4 s = ((const float4*)pbuf)[i];
    #pragma unroll
    for (int sp = 1; sp < 4; sp++) {
        float4 p = ((const float4*)(pbuf + (size_t)sp * 524288))[i];
        s.x += p.x; s.y += p.y; s.z += p.z; s.w += p.w;
    }
    ((float4*)out)[i] = s;
}

// ---------------------------------------------------------------------------
// LayerNorm fp32 [rows][1024] -> bf16, gamma/beta applied
// ---------------------------------------------------------------------------
__global__ __launch_bounds__(256) void ln_kernel(
    const float* __restrict__ x, const float* __restrict__ gamma,
    const float* __restrict__ beta, unsigned short* __restrict__ out)
{
    int row = blockIdx.x;
    int t = threadIdx.x;
    float4 v = ((const float4*)(x + (size_t)row * 1024))[t];
    float s  = v.x + v.y + v.z + v.w;
    float s2 = v.x * v.x + v.y * v.y + v.z * v.z + v.w * v.w;
    #pragma unroll
    for (int o = 32; o > 0; o >>= 1) { s += __shfl_down(s, o); s2 += __shfl_down(s2, o); }
    __shared__ float red[8];
    if ((t & 63) == 0) { red[t >> 6] = s; red[4 + (t >> 6)] = s2; }
    __syncthreads();
    s  = red[0] + red[1] + red[2] + red[3];
    s2 = red[4] + red[5] + red[6] + red[7];
    float mu  = s * (1.0f / 1024.0f);
    float var = s2 * (1.0f / 1024.0f) - mu * mu;
    float rs  = rsqrtf(var + 1e-6f);
    float4 g  = ((const float4*)gamma)[t];
    float4 be = ((const float4*)beta)[t];
    u16x4 o4;
    o4[0] = f2bf((v.x - mu) * rs * g.x + be.x);
    o4[1] = f2bf((v.y - mu) * rs * g.y + be.y);
    o4[2] = f2bf((v.z - mu) * rs * g.z + be.z);
    o4[3] = f2bf((v.w - mu) * rs * g.w + be.w);
    *(u16x4*)(out + (size_t)row * 1024 + t * 4) = o4;
}

// ---------------------------------------------------------------------------
// GEMM 128x128, BK=64, 4 waves (2Mx2N), per-wave 64x64 output.
// 64 KB double-buffered LDS -> 2 blocks/CU (cross-block overlap hides the
// per-tile drain; m103: 128-tile beats 256-tile at this structure).
// Full-tile gload_lds staging (lane-contiguous dest; pre-swizzled global
// source; swizzled ds_read). ONE barrier + ONE vmcnt(0) per K-tile; stage of
// tile t+1 issued at the top of tile t. bf16 epilogues (EP 0/1/3) repack
// through wave-private LDS for full-line stores.
// EP: 0 = store bf16 | 1 = relu+1e-3 bf16 | 2 = +addv f32
//     3 = +bias, gelu, bf16 | 4 = +bias, gelu, +addv, f32
// Requires M%128==0, N%128==0, K%128==0, grid%8==0.
// ---------------------------------------------------------------------------
template <int EP>
__global__ __launch_bounds__(256) void gemm128(
    const unsigned short* __restrict__ A, const unsigned short* __restrict__ Bt,
    void* __restrict__ C, const float* __restrict__ bias,
    const float* __restrict__ addv, int M, int N, int K)
{
    // 65536 B: K-loop uses 2 slots x 16384 elems (A 8192 | B 8192);
    // epilogue reuses buffer as 4 wave-private 4352-elem regions.
    __shared__ unsigned short ldsbuf[32768];
    const int nbn = N >> 7;
    const int nwg = (M >> 7) * nbn;
    int bid = blockIdx.x;
    int wg = (bid & 7) * (nwg >> 3) + (bid >> 3);    // XCD swizzle (nwg%8==0)
    int tm = wg / nbn, tn = wg % nbn;
    const int tid = threadIdx.x;
    const int lane = tid & 63;
    const int l15 = lane & 15, l4 = lane >> 4;
    const int wid = tid >> 6;
    const int wr = wid >> 1, wc = wid & 1;           // 2 x 2 wave grid

    const unsigned short* Ab = A + (size_t)(tm << 7) * K;
    const unsigned short* Bb = Bt + (size_t)(tn << 7) * K;

    const int swz   = (l15 & 7) << 4;
    const int koff0 = (l4 * 16) ^ swz;
    const int koff1 = (64 + l4 * 16) ^ swz;
    const int arow  = wr * 8192 + l15 * 128;         // A row-base bytes (64 rows/wr)
    const int brow  = wc * 8192 + l15 * 128;         // B row-base bytes

    int goff[4];
    #pragma unroll
    for (int i = 0; i < 4; i++) {
        int cid = i * 256 + tid;                     // 1024 chunks = 128 rows x 8
        int row = cid >> 3, c = cid & 7;
        goff[i] = row * K + ((c ^ (row & 7)) << 3);
    }
    const int ld0 = tid * 8;                          // dest elems, + i*2048

    f32x4 acc[4][4] = {};
    const int NT = K >> 6;

#define STAGE_TILE(kt, slot)                                                   \
    {                                                                          \
        int k0_ = (kt) << 6;                                                   \
        _Pragma("unroll")                                                      \
        for (int i_ = 0; i_ < 4; i_++) {                                       \
            gload_lds16(Ab + (size_t)(goff[i_] + k0_), ldsbuf + (slot) * 16384 + ld0 + i_ * 2048); \
            gload_lds16(Bb + (size_t)(goff[i_] + k0_), ldsbuf + (slot) * 16384 + 8192 + ld0 + i_ * 2048); \
        }                                                                      \
    }

#define TILE_STEP(t_, s_)                                                      \
    {                                                                          \
        if ((t_) + 1 < NT) STAGE_TILE((t_) + 1, (s_) ^ 1);                     \
        const char* As_ = (const char*)(ldsbuf + (s_) * 16384);                \
        const char* Bs_ = (const char*)(ldsbuf + (s_) * 16384 + 8192);         \
        bf16x8 a_[4], b_[4];                                                   \
        _Pragma("unroll")                                                      \
        for (int m = 0; m < 4; m++) a_[m] = *(const bf16x8*)(As_ + arow + m * 2048 + koff0); \
        _Pragma("unroll")                                                      \
        for (int n = 0; n < 4; n++) b_[n] = *(const bf16x8*)(Bs_ + brow + n * 2048 + koff0); \
        __builtin_amdgcn_s_setprio(1);                                         \
        _Pragma("unroll")                                                      \
        for (int m = 0; m < 4; m++)                                            \
            _Pragma("unroll")                                                  \
            for (int n = 0; n < 4; n++)                                        \
                acc[m][n] = __builtin_amdgcn_mfma_f32_16x16x32_bf16(a_[m], b_[n], acc[m][n], 0, 0, 0); \
        __builtin_amdgcn_s_setprio(0);                                         \
        _Pragma("unroll")                                                      \
        for (int m = 0; m < 4; m++) a_[m] = *(const bf16x8*)(As_ + arow + m * 2048 + koff1); \
        _Pragma("unroll")                                                      \
        for (int n = 0; n < 4; n++) b_[n] = *(const bf16x8*)(Bs_ + brow + n * 2048 + koff1); \
        __builtin_amdgcn_s_setprio(1);                                         \
        _Pragma("unroll")                                                      \
        for (int m = 0; m < 4; m++)                                            \
            _Pragma("unroll")                                                  \
            for (int n = 0; n < 4; n++)                                        \
                acc[m][n] = __builtin_amdgcn_mfma_f32_16x16x32_bf16(a_[m], b_[n], acc[m][n], 0, 0, 0); \
        __builtin_amdgcn_s_setprio(0);                                         \
        asm volatile("s_waitcnt vmcnt(0)" ::: "memory");                       \
        __builtin_amdgcn_s_barrier();                                          \
    }

    // prologue: stage tile 0 into slot 0
    STAGE_TILE(0, 0);
    asm volatile("s_waitcnt vmcnt(0)" ::: "memory");
    __builtin_amdgcn_s_barrier();

    for (int t = 0; t < NT; t += 2) {
        TILE_STEP(t, 0);
        TILE_STEP(t + 1, 1);
    }
#undef TILE_STEP
#undef STAGE_TILE

    // epilogue (final TILE_STEP barrier guarantees all LDS reads are done)
    int rbase = (tm << 7) + wr * 64;
    int cbase = (tn << 7) + wc * 64;
    if constexpr (EP == 2 || EP == 4) {
        // fp32 outputs: 16 lanes x 4B scalar stores already fill 64B lines
        #pragma unroll
        for (int n = 0; n < 4; n++) {
            int col = cbase + n * 16 + l15;
            float bval = 0.f;
            if constexpr (EP == 4) bval = bias[col];
            #pragma unroll
            for (int mf = 0; mf < 4; mf++) {
                #pragma unroll
                for (int j = 0; j < 4; j++) {
                    int row = rbase + mf * 16 + l4 * 4 + j;
                    float val = acc[mf][n][j];
                    if constexpr (EP == 4) val = gelu_fast(val + bval);
                    ((float*)C)[(size_t)row * N + col] = val + addv[(size_t)row * N + col];
                }
            }
        }
    } else {
        // bf16 outputs: repack via wave-private LDS (stride 68 elems) to
        // 2x8B stores per chunk -> each 8-lane group fills a 128B span.
        unsigned short* myl = ldsbuf + wid * 4352;
        #pragma unroll
        for (int n = 0; n < 4; n++) {
            int col = cbase + n * 16 + l15;
            float bval = 0.f;
            if constexpr (EP == 3) bval = bias[col];
            #pragma unroll
            for (int mf = 0; mf < 4; mf++) {
                #pragma unroll
                for (int j = 0; j < 4; j++) {
                    float val = acc[mf][n][j];
                    if constexpr (EP == 1) val = fmaxf(val, 0.f) + 1e-3f;
                    if constexpr (EP == 3) val = gelu_fast(val + bval);
                    myl[(mf * 16 + l4 * 4 + j) * 68 + n * 16 + l15] = f2bf(val);
                }
            }
        }
        // compiler inserts lgkmcnt(0) before the aliasing reads
        #pragma unroll
        for (int c = 0; c < 8; c++) {
            int lrow = c * 8 + (lane >> 3);
            int cc = (lane & 7) * 8;
            u16x4 lo = *(const u16x4*)(myl + lrow * 68 + cc);
            u16x4 hi = *(const u16x4*)(myl + lrow * 68 + cc + 4);
            unsigned short* dst = (unsigned short*)C + (size_t)(rbase + lrow) * N + cbase + cc;
            *(u16x4*)dst = lo;
            *(u16x4*)(dst + 4) = hi;
        }
    }
}

// ---------------------------------------------------------------------------
// att = (qp @ kvs) / (qp @ ksum), per (b,h), 128-row tiles, in place over qp
// ---------------------------------------------------------------------------
__global__ __launch_bounds__(256) void att_num_kernel(
    const unsigned short* __restrict__ qp, const float* __restrict__ kvsT,
    const float* __restrict__ ksum, unsigned short* __restrict__ att)
{
    int blk = blockIdx.x;
    int t16 = blk & 15, h = (blk >> 4) & 15, b = blk >> 8;
    __shared__ unsigned short Al[128 * 64];
    __shared__ unsigned short Bl[64 * 64];
    __shared__ float kss[64];
    int tid = threadIdx.x;
    int lane = tid & 63, wid = tid >> 6;
    int l15 = lane & 15, l4 = lane >> 4;
    const unsigned short* Ab = qp + ((size_t)(b * 2048 + t16 * 128)) * 1024 + h * 64;
    const float* Bb  = kvsT + (size_t)(b * 16 + h) * 4096;
    const float* ksb = ksum + (b * 16 + h) * 64;
    #pragma unroll
    for (int i = 0; i < 4; i++) {
        int chunk = tid + i * 256;
        int row = chunk >> 3, c = (chunk & 7) * 8;
        u16x8 av = *(const u16x8*)(Ab + (size_t)row * 1024 + c);
        int off = (row * 128 + c * 2) ^ ((row & 7) << 4);
        *(u16x8*)((char*)Al + off) = av;
    }
    #pragma unroll
    for (int i = 0; i < 2; i++) {
        int chunk = tid + i * 256;
        int row = chunk >> 3, c = (chunk & 7) * 8;
        const float* src = Bb + (size_t)row * 64 + c;
        u16x8 bv;
        #pragma unroll
        for (int q = 0; q < 8; q++) bv[q] = f2bf(src[q]);
        int off = (row * 128 + c * 2) ^ ((row & 7) << 4);
        *(u16x8*)((char*)Bl + off) = bv;
    }
    if (tid < 64) kss[tid] = ksb[tid];
    __syncthreads();

    f32x4 acc[2][4] = {};
    #pragma unroll
    for (int kk = 0; kk < 64; kk += 32) {
        bf16x8 af[2], bfr[4];
        #pragma unroll
        for (int m = 0; m < 2; m++) {
            int row = wid * 32 + m * 16 + l15;
            int off = (row * 128 + (kk + l4 * 8) * 2) ^ ((row & 7) << 4);
            af[m] = *(const bf16x8*)((const char*)Al + off);
        }
        #pragma unroll
        for (int n = 0; n < 4; n++) {
            int row = n * 16 + l15;
            int off = (row * 128 + (kk + l4 * 8) * 2) ^ ((row & 7) << 4);
            bfr[n] = *(const bf16x8*)((const char*)Bl + off);
        }
        #pragma unroll
        for (int m = 0; m < 2; m++)
            #pragma unroll
            for (int n = 0; n < 4; n++)
                acc[m][n] = __builtin_amdgcn_mfma_f32_16x16x32_bf16(af[m], bfr[n], acc[m][n], 0, 0, 0);
    }
    __syncthreads();  // everyone done reading Al before in-place writes land

    #pragma unroll
    for (int m = 0; m < 2; m++) {
        #pragma unroll
        for (int j = 0; j < 4; j++) {
            int lrow = wid * 32 + m * 16 + l4 * 4 + j;
            float den = 0.f;
            #pragma unroll
            for (int mm = 0; mm < 64; mm += 8) {
                int off = (lrow * 128 + mm * 2) ^ ((lrow & 7) << 4);
                u16x8 a8 = *(const u16x8*)((const char*)Al + off);
                #pragma unroll
                for (int q = 0; q < 8; q++) den += bf2f(a8[q]) * kss[mm + q];
            }
            float rden = 1.0f / den;
            size_t grow = (size_t)(b * 2048 + t16 * 128 + lrow);
            #pragma unroll
            for (int n = 0; n < 4; n++) {
                int col = h * 64 + n * 16 + l15;
                att[grow * 1024 + col] = f2bf(acc[m][n][j] * rden);
            }
        }
    }
}

// ---------------------------------------------------------------------------
extern "C" void kernel_launch(void* const* d_in, const int* in_sizes, int n_in,
                              void* d_out, int out_size, void* d_ws, size_t ws_size,
                              hipStream_t stream) {
    (void)in_sizes; (void)n_in; (void)out_size; (void)ws_size;
    const float* x      = (const float*)d_in[0];
    const float* gamma1 = (const float*)d_in[1];
    const float* beta1  = (const float*)d_in[2];
    const float* wq     = (const float*)d_in[3];
    const float* wk     = (const float*)d_in[4];
    const float* wv     = (const float*)d_in[5];
    const float* wo     = (const float*)d_in[6];
    const float* w1     = (const float*)d_in[7];
    const float* b1     = (const float*)d_in[8];
    const float* w2     = (const float*)d_in[9];
    const float* b2     = (const float*)d_in[10];
    float* out = (float*)d_out;

    const size_t MB = 1024 * 1024;
    char* ws = (char*)d_ws;
    unsigned short* wq_bt = (unsigned short*)(ws + 0 * MB);
    unsigned short* wk_bt = (unsigned short*)(ws + 2 * MB);
    unsigned short* wv_bt = (unsigned short*)(ws + 4 * MB);
    unsigned short* wo_bt = (unsigned short*)(ws + 6 * MB);
    unsigned short* w1_bt = (unsigned short*)(ws + 8 * MB);
    unsigned short* w2_bt = (unsigned short*)(ws + 16 * MB);
    unsigned short* lnbuf = (unsigned short*)(ws + 24 * MB);   // 32 MB (ln1 then ln2)
    float*          add1  = (float*)(ws + 56 * MB);            // 64 MB fp32
    float*          pbuf  = (float*)(ws + 88 * MB);            // 8 MB partials
    unsigned short* qp    = (unsigned short*)(ws + 120 * MB);  // 32 MB (att in-place later)
    unsigned short* kpT   = (unsigned short*)(ws + 152 * MB);  // 32 MB [1024 feat][16384 l]
    unsigned short* vT    = (unsigned short*)(ws + 184 * MB);  // 32 MB [1024 feat][16384 l]
    float*          kvsT  = (float*)(ws + 216 * MB);           // 2 MB
    float*          ksum  = (float*)(ws + 218 * MB);           // 32 KB
    unsigned short* hbuf  = (unsigned short*)(ws + 120 * MB);  // 128 MB, reuses qp..kvsT region

    dim3 blk(256);
    // weights -> bf16 transposed [N][K]
    transpose_w<<<dim3(256),  blk, 0, stream>>>(wq, wq_bt, 1024, 1024);
    transpose_w<<<dim3(256),  blk, 0, stream>>>(wk, wk_bt, 1024, 1024);
    transpose_w<<<dim3(256),  blk, 0, stream>>>(wv, wv_bt, 1024, 1024);
    transpose_w<<<dim3(256),  blk, 0, stream>>>(wo, wo_bt, 1024, 1024);
    transpose_w<<<dim3(1024), blk, 0, stream>>>(w1, w1_bt, 1024, 4096);
    transpose_w<<<dim3(1024), blk, 0, stream>>>(w2, w2_bt, 4096, 1024);
    // ln1
    ln_kernel<<<dim3(16384), blk, 0, stream>>>(x, gamma1, beta1, lnbuf);
    // Q normal orientation; K,V output-transposed (A=weight, Bt=lnbuf)
    gemm128<1><<<dim3(1024), blk, 0, stream>>>(lnbuf, wq_bt, qp, nullptr, nullptr, 16384, 1024, 1024);
    gemm128<1><<<dim3(1024), blk, 0, stream>>>(wk_bt, lnbuf, kpT, nullptr, nullptr, 1024, 16384, 1024);
    gemm128<0><<<dim3(1024), blk, 0, stream>>>(wv_bt, lnbuf, vT, nullptr, nullptr, 1024, 16384, 1024);
    // ksum; kvs via MFMA split-K; reduce
    ksum_kernel<<<dim3(2048), blk, 0, stream>>>(kpT, ksum);
    kvs_mfma<<<dim3(512), blk, 0, stream>>>(vT, kpT, pbuf);
    reduce4<<<dim3(512), blk, 0, stream>>>(pbuf, kvsT);
    // att = (qp@kvs)/(qp@ksum), in place over qp
    att_num_kernel<<<dim3(2048), blk, 0, stream>>>(qp, kvsT, ksum, qp);
    // attn_out = att @ wo, + x -> add1 (fp32)
    gemm128<2><<<dim3(1024), blk, 0, stream>>>(qp, wo_bt, add1, nullptr, x, 16384, 1024, 1024);
    // ln2 (reference reuses gamma1/beta1)
    ln_kernel<<<dim3(16384), blk, 0, stream>>>(add1, gamma1, beta1, lnbuf);
    // FFN
    gemm128<3><<<dim3(4096), blk, 0, stream>>>(lnbuf, w1_bt, hbuf, b1, nullptr, 16384, 4096, 1024);
    gemm128<4><<<dim3(1024), blk, 0, stream>>>(hbuf, w2_bt, out, b2, add1, 16384, 1024, 4096);
}

// Round 14
// 594.814 us; speedup vs baseline: 1.1149x; 1.1149x over previous
//
#include <hip/hip_runtime.h>
#include <hip/hip_bf16.h>
#include <math.h>

typedef float f32x4 __attribute__((ext_vector_type(4)));
typedef __bf16 bf16x8 __attribute__((ext_vector_type(8)));
typedef unsigned short u16x8 __attribute__((ext_vector_type(8)));
typedef unsigned short u16x4 __attribute__((ext_vector_type(4)));

__device__ __forceinline__ float bf2f(unsigned short u) {
    unsigned int x = ((unsigned int)u) << 16;
    float f; __builtin_memcpy(&f, &x, 4); return f;
}
__device__ __forceinline__ unsigned short f2bf(float f) {
    unsigned int x; __builtin_memcpy(&x, &f, 4);
    unsigned int r = x + 0x7fffu + ((x >> 16) & 1u);
    return (unsigned short)(r >> 16);
}
// tanh-form GELU via hardware exp/rcp (~8 VALU ops vs ~40 for erff).
__device__ __forceinline__ float gelu_fast(float v) {
    float z2 = v * (1.5957691216f + 0.0713548162f * v * v);
    float e  = __expf(z2);
    float t  = 1.0f - 2.0f * __builtin_amdgcn_rcpf(1.0f + e);
    return 0.5f * v * (1.0f + t);
}
// async global -> LDS, 16 bytes per lane (global_load_lds_dwordx4)
__device__ __forceinline__ void gload_lds16(const unsigned short* g, unsigned short* l) {
    __builtin_amdgcn_global_load_lds(
        (const __attribute__((address_space(1))) unsigned int*)g,
        (__attribute__((address_space(3))) unsigned int*)l, 16, 0, 0);
}

// ---------------------------------------------------------------------------
// Weight transpose: fp32 [K][N] -> bf16 [N][K]
// ---------------------------------------------------------------------------
__global__ __launch_bounds__(256) void transpose_w(
    const float* __restrict__ in, unsigned short* __restrict__ out, int K, int N)
{
    __shared__ unsigned short tile[64][72];
    int nbn = N >> 6;
    int tk = (blockIdx.x / nbn) << 6;
    int tn = (blockIdx.x % nbn) << 6;
    int t = threadIdx.x;
    int r = t >> 2, c0 = (t & 3) * 16;
    #pragma unroll
    for (int i = 0; i < 16; i += 4) {
        float4 f = *(const float4*)(in + (size_t)(tk + r) * N + tn + c0 + i);
        tile[r][c0 + i + 0] = f2bf(f.x);
        tile[r][c0 + i + 1] = f2bf(f.y);
        tile[r][c0 + i + 2] = f2bf(f.z);
        tile[r][c0 + i + 3] = f2bf(f.w);
    }
    __syncthreads();
    u16x8 o0, o1;
    #pragma unroll
    for (int i = 0; i < 8; i++) { o0[i] = tile[c0 + i][r]; o1[i] = tile[c0 + 8 + i][r]; }
    *(u16x8*)(out + (size_t)(tn + r) * K + tk + c0)     = o0;
    *(u16x8*)(out + (size_t)(tn + r) * K + tk + c0 + 8) = o1;
}

// ---------------------------------------------------------------------------
// kvs partial GEMM + fused ksum:
//   pbuf[sp][bh][d][m] = sum_{l in sp-chunk} vT[d][l]*kpT[m][l]
//   ksum[bh*64+m]     += sum_{l in sp-chunk} kpT[m][l]   (atomic)
// vT/kpT layout: [1024 features][16384 l]; block (bh, sp) covers 512 l's.
// ---------------------------------------------------------------------------
__global__ __launch_bounds__(256) void kvs_mfma(
    const unsigned short* __restrict__ vT, const unsigned short* __restrict__ kpT,
    float* __restrict__ pbuf, float* __restrict__ ksum)
{
    int blk = blockIdx.x;
    int bh = blk >> 2, sp = blk & 3;
    int b = bh >> 4, h = bh & 15;
    const unsigned short* Abase = vT  + (size_t)(h * 64) * 16384 + b * 2048 + sp * 512;
    const unsigned short* Bbase = kpT + (size_t)(h * 64) * 16384 + b * 2048 + sp * 512;
    __shared__ unsigned short Al[64 * 64];
    __shared__ unsigned short Bl[64 * 64];
    int t = threadIdx.x;
    int lane = t & 63, wid = t >> 6;
    int l15 = lane & 15, l4 = lane >> 4;
    int wr = wid >> 1, wc = wid & 1;
    f32x4 acc[2][2] = {};
    float ks0 = 0.f, ks1 = 0.f;   // partial row-sums for rows t>>3 and 32+(t>>3)
    for (int k0 = 0; k0 < 512; k0 += 64) {
        #pragma unroll
        for (int i = 0; i < 2; i++) {
            int chunk = i * 256 + t;
            int row = chunk >> 3, c = (chunk & 7) * 8;
            u16x8 av = *(const u16x8*)(Abase + (size_t)row * 16384 + k0 + c);
            u16x8 bv = *(const u16x8*)(Bbase + (size_t)row * 16384 + k0 + c);
            float s = 0.f;
            #pragma unroll
            for (int q = 0; q < 8; q++) s += bf2f(bv[q]);
            if (i == 0) ks0 += s; else ks1 += s;
            int off = (row * 128 + c * 2) ^ ((row & 7) << 4);
            *(u16x8*)((char*)Al + off) = av;
            *(u16x8*)((char*)Bl + off) = bv;
        }
        __syncthreads();
        #pragma unroll
        for (int kh = 0; kh < 2; kh++) {
            bf16x8 af[2], bf[2];
            #pragma unroll
            for (int mi = 0; mi < 2; mi++) {
                int row = wr * 32 + mi * 16 + l15;
                int off = (row * 128 + (kh * 32 + l4 * 8) * 2) ^ ((row & 7) << 4);
                af[mi] = *(const bf16x8*)((const char*)Al + off);
            }
            #pragma unroll
            for (int ni = 0; ni < 2; ni++) {
                int row = wc * 32 + ni * 16 + l15;
                int off = (row * 128 + (kh * 32 + l4 * 8) * 2) ^ ((row & 7) << 4);
                bf[ni] = *(const bf16x8*)((const char*)Bl + off);
            }
            #pragma unroll
            for (int mi = 0; mi < 2; mi++)
                #pragma unroll
                for (int ni = 0; ni < 2; ni++)
                    acc[mi][ni] = __builtin_amdgcn_mfma_f32_16x16x32_bf16(af[mi], bf[ni], acc[mi][ni], 0, 0, 0);
        }
        __syncthreads();
    }
    // ksum reduce: rows t>>3 (ks0) and 32+(t>>3) (ks1), 8 consecutive lanes/row
    #pragma unroll
    for (int o = 4; o > 0; o >>= 1) { ks0 += __shfl_down(ks0, o); ks1 += __shfl_down(ks1, o); }
    if ((t & 7) == 0) {
        atomicAdd(&ksum[bh * 64 + (t >> 3)], ks0);
        atomicAdd(&ksum[bh * 64 + 32 + (t >> 3)], ks1);
    }
    float* pb = pbuf + ((size_t)sp * 128 + bh) * 4096;
    #pragma unroll
    for (int mi = 0; mi < 2; mi++)
        #pragma unroll
        for (int ni = 0; ni < 2; ni++)
            #pragma unroll
            for (int j = 0; j < 4; j++) {
                int d = wr * 32 + mi * 16 + l4 * 4 + j;
                int m = wc * 32 + ni * 16 + l15;
                pb[d * 64 + m] = acc[mi][ni][j];
            }
}

// ---------------------------------------------------------------------------
// LayerNorm fp32 [rows][1024] -> bf16, gamma/beta applied
// ---------------------------------------------------------------------------
__global__ __launch_bounds__(256) void ln_kernel(
    const float* __restrict__ x, const float* __restrict__ gamma,
    const float* __restrict__ beta, unsigned short* __restrict__ out)
{
    int row = blockIdx.x;
    int t = threadIdx.x;
    float4 v = ((const float4*)(x + (size_t)row * 1024))[t];
    float s  = v.x + v.y + v.z + v.w;
    float s2 = v.x * v.x + v.y * v.y + v.z * v.z + v.w * v.w;
    #pragma unroll
    for (int o = 32; o > 0; o >>= 1) { s += __shfl_down(s, o); s2 += __shfl_down(s2, o); }
    __shared__ float red[8];
    if ((t & 63) == 0) { red[t >> 6] = s; red[4 + (t >> 6)] = s2; }
    __syncthreads();
    s  = red[0] + red[1] + red[2] + red[3];
    s2 = red[4] + red[5] + red[6] + red[7];
    float mu  = s * (1.0f / 1024.0f);
    float var = s2 * (1.0f / 1024.0f) - mu * mu;
    float rs  = rsqrtf(var + 1e-6f);
    float4 g  = ((const float4*)gamma)[t];
    float4 be = ((const float4*)beta)[t];
    u16x4 o4;
    o4[0] = f2bf((v.x - mu) * rs * g.x + be.x);
    o4[1] = f2bf((v.y - mu) * rs * g.y + be.y);
    o4[2] = f2bf((v.z - mu) * rs * g.z + be.z);
    o4[3] = f2bf((v.w - mu) * rs * g.w + be.w);
    *(u16x4*)(out + (size_t)row * 1024 + t * 4) = o4;
}

// ---------------------------------------------------------------------------
// LayerNorm bf16 [rows][1024] -> bf16
// ---------------------------------------------------------------------------
__global__ __launch_bounds__(256) void ln_bf16_kernel(
    const unsigned short* __restrict__ x, const float* __restrict__ gamma,
    const float* __restrict__ beta, unsigned short* __restrict__ out)
{
    int row = blockIdx.x;
    int t = threadIdx.x;
    u16x4 uv = ((const u16x4*)(x + (size_t)row * 1024))[t];
    float v0 = bf2f(uv[0]), v1 = bf2f(uv[1]), v2 = bf2f(uv[2]), v3 = bf2f(uv[3]);
    float s  = v0 + v1 + v2 + v3;
    float s2 = v0 * v0 + v1 * v1 + v2 * v2 + v3 * v3;
    #pragma unroll
    for (int o = 32; o > 0; o >>= 1) { s += __shfl_down(s, o); s2 += __shfl_down(s2, o); }
    __shared__ float red[8];
    if ((t & 63) == 0) { red[t >> 6] = s; red[4 + (t >> 6)] = s2; }
    __syncthreads();
    s  = red[0] + red[1] + red[2] + red[3];
    s2 = red[4] + red[5] + red[6] + red[7];
    float mu  = s * (1.0f / 1024.0f);
    float var = s2 * (1.0f / 1024.0f) - mu * mu;
    float rs  = rsqrtf(var + 1e-6f);
    float4 g  = ((const float4*)gamma)[t];
    float4 be = ((const float4*)beta)[t];
    u16x4 o4;
    o4[0] = f2bf((v0 - mu) * rs * g.x + be.x);
    o4[1] = f2bf((v1 - mu) * rs * g.y + be.y);
    o4[2] = f2bf((v2 - mu) * rs * g.z + be.z);
    o4[3] = f2bf((v3 - mu) * rs * g.w + be.w);
    *(u16x4*)(out + (size_t)row * 1024 + t * 4) = o4;
}

// ---------------------------------------------------------------------------
// GEMM 256x256, BK=64, 8 waves (2Mx4N) — round-12 proven structure.
// EP: 0 = bf16 | 1 = relu+1e-3 bf16 | 5 = row-cond relu (tm<4) bf16
//     2 = +addv(f32) -> bf16 | 3 = +bias, gelu, bf16
//     4 = +bias, gelu, +addv(bf16) -> f32
// Requires M%256==0, N%256==0, K%128==0, grid%8==0.
// ---------------------------------------------------------------------------
template <int EP>
__global__ __launch_bounds__(512) void gemm256(
    const unsigned short* __restrict__ A, const unsigned short* __restrict__ Bt,
    void* __restrict__ C, const float* __restrict__ bias,
    const void* __restrict__ addv, int M, int N, int K)
{
    __shared__ unsigned short ldsbuf[69632];
    const int nbn = N >> 8;
    const int nwg = (M >> 8) * nbn;
    int bid = blockIdx.x;
    int wg = (bid & 7) * (nwg >> 3) + (bid >> 3);    // XCD swizzle (nwg%8==0)
    int tm = wg / nbn, tn = wg % nbn;
    const int tid = threadIdx.x;
    const int lane = tid & 63;
    const int l15 = lane & 15, l4 = lane >> 4;
    const int wid = tid >> 6;
    const int wr = wid >> 2, wc = wid & 3;           // 2 x 4 wave grid

    const unsigned short* Ab = A + (size_t)(tm << 8) * K;
    const unsigned short* Bb = Bt + (size_t)(tn << 8) * K;

    const int swz   = (l15 & 7) << 4;
    const int koff0 = (l4 * 16) ^ swz;
    const int koff1 = (64 + l4 * 16) ^ swz;
    const int arow  = wr * 16384 + l15 * 128;
    const int brow  = wc * 8192  + l15 * 128;

    int goff[4];
    #pragma unroll
    for (int i = 0; i < 4; i++) {
        int cid = i * 512 + tid;
        int row = cid >> 3, c = cid & 7;
        goff[i] = row * K + ((c ^ (row & 7)) << 3);
    }
    const int ld0 = tid * 8;

    f32x4 acc[8][4] = {};
    const int NT = K >> 6;

#define STAGE_TILE(kt, slot)                                                   \
    {                                                                          \
        int k0_ = (kt) << 6;                                                   \
        _Pragma("unroll")                                                      \
        for (int i_ = 0; i_ < 4; i_++) {                                       \
            gload_lds16(Ab + (size_t)(goff[i_] + k0_), ldsbuf + (slot) * 32768 + ld0 + i_ * 4096); \
            gload_lds16(Bb + (size_t)(goff[i_] + k0_), ldsbuf + (slot) * 32768 + 16384 + ld0 + i_ * 4096); \
        }                                                                      \
    }

#define TILE_STEP(t_, s_)                                                      \
    {                                                                          \
        if ((t_) + 1 < NT) STAGE_TILE((t_) + 1, (s_) ^ 1);                     \
        const char* As_ = (const char*)(ldsbuf + (s_) * 32768);                \
        const char* Bs_ = (const char*)(ldsbuf + (s_) * 32768 + 16384);        \
        bf16x8 a_[8], b_[4];                                                   \
        _Pragma("unroll")                                                      \
        for (int m = 0; m < 8; m++) a_[m] = *(const bf16x8*)(As_ + arow + m * 2048 + koff0); \
        _Pragma("unroll")                                                      \
        for (int n = 0; n < 4; n++) b_[n] = *(const bf16x8*)(Bs_ + brow + n * 2048 + koff0); \
        __builtin_amdgcn_s_setprio(1);                                         \
        _Pragma("unroll")                                                      \
        for (int m = 0; m < 8; m++)                                            \
            _Pragma("unroll")                                                  \
            for (int n = 0; n < 4; n++)                                        \
                acc[m][n] = __builtin_amdgcn_mfma_f32_16x16x32_bf16(a_[m], b_[n], acc[m][n], 0, 0, 0); \
        __builtin_amdgcn_s_setprio(0);                                         \
        _Pragma("unroll")                                                      \
        for (int m = 0; m < 8; m++) a_[m] = *(const bf16x8*)(As_ + arow + m * 2048 + koff1); \
        _Pragma("unroll")                                                      \
        for (int n = 0; n < 4; n++) b_[n] = *(const bf16x8*)(Bs_ + brow + n * 2048 + koff1); \
        __builtin_amdgcn_s_setprio(1);                                         \
        _Pragma("unroll")                                                      \
        for (int m = 0; m < 8; m++)                                            \
            _Pragma("unroll")                                                  \
            for (int n = 0; n < 4; n++)                                        \
                acc[m][n] = __builtin_amdgcn_mfma_f32_16x16x32_bf16(a_[m], b_[n], acc[m][n], 0, 0, 0); \
        __builtin_amdgcn_s_setprio(0);                                         \
        asm volatile("s_waitcnt vmcnt(0)" ::: "memory");                       \
        __builtin_amdgcn_s_barrier();                                          \
    }

    STAGE_TILE(0, 0);
    asm volatile("s_waitcnt vmcnt(0)" ::: "memory");
    __builtin_amdgcn_s_barrier();

    for (int t = 0; t < NT; t += 2) {
        TILE_STEP(t, 0);
        TILE_STEP(t + 1, 1);
    }
#undef TILE_STEP
#undef STAGE_TILE

    int rbase = (tm << 8) + wr * 128;
    int cbase = (tn << 8) + wc * 64;
    if constexpr (EP == 4) {
        // fp32 out = gelu(val+bias) + bf16 addv; 16 lanes x 4B fill 64B lines
        const unsigned short* av16 = (const unsigned short*)addv;
        #pragma unroll
        for (int n = 0; n < 4; n++) {
            int col = cbase + n * 16 + l15;
            float bval = bias[col];
            #pragma unroll
            for (int mf = 0; mf < 8; mf++) {
                #pragma unroll
                for (int j = 0; j < 4; j++) {
                    int row = rbase + mf * 16 + l4 * 4 + j;
                    float val = gelu_fast(acc[mf][n][j] + bval);
                    ((float*)C)[(size_t)row * N + col] = val + bf2f(av16[(size_t)row * N + col]);
                }
            }
        }
    } else {
        // bf16 outputs: repack via wave-private LDS (stride 68) -> full lines
        const float* avf = (const float*)addv;
        unsigned short* myl = ldsbuf + wid * 8704;
        #pragma unroll
        for (int n = 0; n < 4; n++) {
            int col = cbase + n * 16 + l15;
            float bval = 0.f;
            if constexpr (EP == 3) bval = bias[col];
            #pragma unroll
            for (int mf = 0; mf < 8; mf++) {
                #pragma unroll
                for (int j = 0; j < 4; j++) {
                    int row = rbase + mf * 16 + l4 * 4 + j;
                    float val = acc[mf][n][j];
                    if constexpr (EP == 1) val = fmaxf(val, 0.f) + 1e-3f;
                    if constexpr (EP == 5) { if (tm < 4) val = fmaxf(val, 0.f) + 1e-3f; }
                    if constexpr (EP == 3) val = gelu_fast(val + bval);
                    if constexpr (EP == 2) val += avf[(size_t)row * N + col];
                    myl[(mf * 16 + l4 * 4 + j) * 68 + n * 16 + l15] = f2bf(val);
                }
            }
        }
        #pragma unroll
        for (int c = 0; c < 16; c++) {
            int lrow = c * 8 + (lane >> 3);
            int cc = (lane & 7) * 8;
            u16x4 lo = *(const u16x4*)(myl + lrow * 68 + cc);
            u16x4 hi = *(const u16x4*)(myl + lrow * 68 + cc + 4);
            unsigned short* dst = (unsigned short*)C + (size_t)(rbase + lrow) * N + cbase + cc;
            *(u16x4*)dst = lo;
            *(u16x4*)(dst + 4) = hi;
        }
    }
}

// ---------------------------------------------------------------------------
// att = (qp @ sum_sp pbuf) / (qp @ ksum), per (b,h), 128-row tiles, in place
// over qp. reduce4 fused into the Bl staging.
// ---------------------------------------------------------------------------
__global__ __launch_bounds__(256) void att_num_kernel(
    const unsigned short* __restrict__ qp, const float* __restrict__ pbuf,
    const float* __restrict__ ksum, unsigned short* __restrict__ att)
{
    int blk = blockIdx.x;
    int t16 = blk & 15, h = (blk >> 4) & 15, b = blk >> 8;
    int bh = b * 16 + h;
    __shared__ unsigned short Al[128 * 64];
    __shared__ unsigned short Bl[64 * 64];
    __shared__ float kss[64];
    int tid = threadIdx.x;
    int lane = tid & 63, wid = tid >> 6;
    int l15 = lane & 15, l4 = lane >> 4;
    const unsigned short* Ab = qp + ((size_t)(b * 2048 + t16 * 128)) * 1024 + h * 64;
    const float* Bb  = pbuf + (size_t)bh * 4096;
    const float* ksb = ksum + bh * 64;
    #pragma unroll
    for (int i = 0; i < 4; i++) {
        int chunk = tid + i * 256;
        int row = chunk >> 3, c = (chunk & 7) * 8;
        u16x8 av = *(const u16x8*)(Ab + (size_t)row * 1024 + c);
        int off = (row * 128 + c * 2) ^ ((row & 7) << 4);
        *(u16x8*)((char*)Al + off) = av;
    }
    #pragma unroll
    for (int i = 0; i < 2; i++) {
        int chunk = tid + i * 256;
        int row = chunk >> 3, c = (chunk & 7) * 8;
        float sum8[8] = {};
        #pragma unroll
        for (int sp = 0; sp < 4; sp++) {
            const float* src = Bb + (size_t)sp * 524288 + row * 64 + c;
            #pragma unroll
            for (int q = 0; q < 8; q++) sum8[q] += src[q];
        }
        u16x8 bv;
        #pragma unroll
        for (int q = 0; q < 8; q++) bv[q] = f2bf(sum8[q]);
        int off = (row * 128 + c * 2) ^ ((row & 7) << 4);
        *(u16x8*)((char*)Bl + off) = bv;
    }
    if (tid < 64) kss[tid] = ksb[tid];
    __syncthreads();

    f32x4 acc[2][4] = {};
    #pragma unroll
    for (int kk = 0; kk < 64; kk += 32) {
        bf16x8 af[2], bfr[4];
        #pragma unroll
        for (int m = 0; m < 2; m++) {
            int row = wid * 32 + m * 16 + l15;
            int off = (row * 128 + (kk + l4 * 8) * 2) ^ ((row & 7) << 4);
            af[m] = *(const bf16x8*)((const char*)Al + off);
        }
        #pragma unroll
        for (int n = 0; n < 4; n++) {
            int row = n * 16 + l15;
            int off = (row * 128 + (kk + l4 * 8) * 2) ^ ((row & 7) << 4);
            bfr[n] = *(const bf16x8*)((const char*)Bl + off);
        }
        #pragma unroll
        for (int m = 0; m < 2; m++)
            #pragma unroll
            for (int n = 0; n < 4; n++)
                acc[m][n] = __builtin_amdgcn_mfma_f32_16x16x32_bf16(af[m], bfr[n], acc[m][n], 0, 0, 0);
    }
    __syncthreads();  // everyone done reading Al before in-place writes land

    #pragma unroll
    for (int m = 0; m < 2; m++) {
        #pragma unroll
        for (int j = 0; j < 4; j++) {
            int lrow = wid * 32 + m * 16 + l4 * 4 + j;
            float den = 0.f;
            #pragma unroll
            for (int mm = 0; mm < 64; mm += 8) {
                int off = (lrow * 128 + mm * 2) ^ ((lrow & 7) << 4);
                u16x8 a8 = *(const u16x8*)((const char*)Al + off);
                #pragma unroll
                for (int q = 0; q < 8; q++) den += bf2f(a8[q]) * kss[mm + q];
            }
            float rden = 1.0f / den;
            size_t grow = (size_t)(b * 2048 + t16 * 128 + lrow);
            #pragma unroll
            for (int n = 0; n < 4; n++) {
                int col = h * 64 + n * 16 + l15;
                att[grow * 1024 + col] = f2bf(acc[m][n][j] * rden);
            }
        }
    }
}

// ---------------------------------------------------------------------------
extern "C" void kernel_launch(void* const* d_in, const int* in_sizes, int n_in,
                              void* d_out, int out_size, void* d_ws, size_t ws_size,
                              hipStream_t stream) {
    (void)in_sizes; (void)n_in; (void)out_size; (void)ws_size;
    const float* x      = (const float*)d_in[0];
    const float* gamma1 = (const float*)d_in[1];
    const float* beta1  = (const float*)d_in[2];
    const float* wq     = (const float*)d_in[3];
    const float* wk     = (const float*)d_in[4];
    const float* wv     = (const float*)d_in[5];
    const float* wo     = (const float*)d_in[6];
    const float* w1     = (const float*)d_in[7];
    const float* b1     = (const float*)d_in[8];
    const float* w2     = (const float*)d_in[9];
    const float* b2     = (const float*)d_in[10];
    float* out = (float*)d_out;

    const size_t MB = 1024 * 1024;
    char* ws = (char*)d_ws;
    unsigned short* wq_bt = (unsigned short*)(ws + 0 * MB);
    unsigned short* wk_bt = (unsigned short*)(ws + 2 * MB);   // wk_bt+wv_bt contiguous (4 MB)
    unsigned short* wv_bt = (unsigned short*)(ws + 4 * MB);
    unsigned short* wo_bt = (unsigned short*)(ws + 6 * MB);
    unsigned short* w1_bt = (unsigned short*)(ws + 8 * MB);
    unsigned short* w2_bt = (unsigned short*)(ws + 16 * MB);
    unsigned short* lnbuf = (unsigned short*)(ws + 24 * MB);   // 32 MB (ln1 then ln2)
    unsigned short* add1b = (unsigned short*)(ws + 56 * MB);   // 32 MB bf16 residual
    float*          pbuf  = (float*)(ws + 88 * MB);            // 8 MB partials
    unsigned short* qp    = (unsigned short*)(ws + 120 * MB);  // 32 MB (att in-place later)
    unsigned short* kpT   = (unsigned short*)(ws + 152 * MB);  // 32 MB [1024 feat][16384 l]
    unsigned short* vT    = (unsigned short*)(ws + 184 * MB);  // 32 MB (contiguous after kpT)
    float*          ksum  = (float*)(ws + 218 * MB);           // 32 KB
    unsigned short* hbuf  = (unsigned short*)(ws + 120 * MB);  // 128 MB, reuses qp..region

    dim3 blk(256), blk512(512);
    // weights -> bf16 transposed [N][K]
    transpose_w<<<dim3(256),  blk, 0, stream>>>(wq, wq_bt, 1024, 1024);
    transpose_w<<<dim3(256),  blk, 0, stream>>>(wk, wk_bt, 1024, 1024);
    transpose_w<<<dim3(256),  blk, 0, stream>>>(wv, wv_bt, 1024, 1024);
    transpose_w<<<dim3(256),  blk, 0, stream>>>(wo, wo_bt, 1024, 1024);
    transpose_w<<<dim3(1024), blk, 0, stream>>>(w1, w1_bt, 1024, 4096);
    transpose_w<<<dim3(1024), blk, 0, stream>>>(w2, w2_bt, 4096, 1024);
    // ln1
    ln_kernel<<<dim3(16384), blk, 0, stream>>>(x, gamma1, beta1, lnbuf);
    // Q row-major; K+V fused output-transposed (A = [wk_bt;wv_bt], M=2048):
    // rows 0-1023 -> kpT (relu+stab via EP5 tm<4), rows 1024-2047 -> vT
    gemm256<1><<<dim3(256), blk512, 0, stream>>>(lnbuf, wq_bt, qp, nullptr, nullptr, 16384, 1024, 1024);
    gemm256<5><<<dim3(512), blk512, 0, stream>>>(wk_bt, lnbuf, kpT, nullptr, nullptr, 2048, 16384, 1024);
    // kvs (split-K MFMA, fused ksum)
    hipMemsetAsync(ksum, 0, 32 * 1024, stream);
    kvs_mfma<<<dim3(512), blk, 0, stream>>>(vT, kpT, pbuf, ksum);
    // att = (qp@kvs)/(qp@ksum), in place over qp (reduce4 fused)
    att_num_kernel<<<dim3(2048), blk, 0, stream>>>(qp, pbuf, ksum, qp);
    // attn_out = att @ wo, + x -> add1 (bf16)
    gemm256<2><<<dim3(256), blk512, 0, stream>>>(qp, wo_bt, add1b, nullptr, x, 16384, 1024, 1024);
    // ln2 on bf16 residual
    ln_bf16_kernel<<<dim3(16384), blk, 0, stream>>>(add1b, gamma1, beta1, lnbuf);
    // FFN
    gemm256<3><<<dim3(1024), blk512, 0, stream>>>(lnbuf, w1_bt, hbuf, b1, nullptr, 16384, 4096, 1024);
    gemm256<4><<<dim3(256),  blk512, 0, stream>>>(hbuf, w2_bt, out, b2, add1b, 16384, 1024, 4096);
}

// Round 16
// 592.251 us; speedup vs baseline: 1.1198x; 1.0043x over previous
//
#include <hip/hip_runtime.h>
#include <hip/hip_bf16.h>
#include <math.h>

typedef float f32x4 __attribute__((ext_vector_type(4)));
typedef __bf16 bf16x8 __attribute__((ext_vector_type(8)));
typedef unsigned short u16x8 __attribute__((ext_vector_type(8)));
typedef unsigned short u16x4 __attribute__((ext_vector_type(4)));

__device__ __forceinline__ float bf2f(unsigned short u) {
    unsigned int x = ((unsigned int)u) << 16;
    float f; __builtin_memcpy(&f, &x, 4); return f;
}
__device__ __forceinline__ unsigned short f2bf(float f) {
    unsigned int x; __builtin_memcpy(&x, &f, 4);
    unsigned int r = x + 0x7fffu + ((x >> 16) & 1u);
    return (unsigned short)(r >> 16);
}
// tanh-form GELU via hardware exp/rcp (~8 VALU ops vs ~40 for erff).
__device__ __forceinline__ float gelu_fast(float v) {
    float z2 = v * (1.5957691216f + 0.0713548162f * v * v);
    float e  = __expf(z2);
    float t  = 1.0f - 2.0f * __builtin_amdgcn_rcpf(1.0f + e);
    return 0.5f * v * (1.0f + t);
}
// async global -> LDS, 16 bytes per lane (global_load_lds_dwordx4)
__device__ __forceinline__ void gload_lds16(const unsigned short* g, unsigned short* l) {
    __builtin_amdgcn_global_load_lds(
        (const __attribute__((address_space(1))) unsigned int*)g,
        (__attribute__((address_space(3))) unsigned int*)l, 16, 0, 0);
}

// ---------------------------------------------------------------------------
// Weight transpose: fp32 [K][N] -> bf16 [N][K]
// ---------------------------------------------------------------------------
__global__ __launch_bounds__(256) void transpose_w(
    const float* __restrict__ in, unsigned short* __restrict__ out, int K, int N)
{
    __shared__ unsigned short tile[64][72];
    int nbn = N >> 6;
    int tk = (blockIdx.x / nbn) << 6;
    int tn = (blockIdx.x % nbn) << 6;
    int t = threadIdx.x;
    int r = t >> 2, c0 = (t & 3) * 16;
    #pragma unroll
    for (int i = 0; i < 16; i += 4) {
        float4 f = *(const float4*)(in + (size_t)(tk + r) * N + tn + c0 + i);
        tile[r][c0 + i + 0] = f2bf(f.x);
        tile[r][c0 + i + 1] = f2bf(f.y);
        tile[r][c0 + i + 2] = f2bf(f.z);
        tile[r][c0 + i + 3] = f2bf(f.w);
    }
    __syncthreads();
    u16x8 o0, o1;
    #pragma unroll
    for (int i = 0; i < 8; i++) { o0[i] = tile[c0 + i][r]; o1[i] = tile[c0 + 8 + i][r]; }
    *(u16x8*)(out + (size_t)(tn + r) * K + tk + c0)     = o0;
    *(u16x8*)(out + (size_t)(tn + r) * K + tk + c0 + 8) = o1;
}

// ---------------------------------------------------------------------------
// kvs partial GEMM + fused ksum:
//   pbuf[sp][bh][d][m] = sum_{l in sp-chunk} vT[d][l]*kpT[m][l]
//   ksum[bh*64+m]     += sum_{l in sp-chunk} kpT[m][l]   (atomic)
// vT/kpT layout: [1024 features][16384 l]; block (bh, sp) covers 512 l's.
// ---------------------------------------------------------------------------
__global__ __launch_bounds__(256) void kvs_mfma(
    const unsigned short* __restrict__ vT, const unsigned short* __restrict__ kpT,
    float* __restrict__ pbuf, float* __restrict__ ksum)
{
    int blk = blockIdx.x;
    int bh = blk >> 2, sp = blk & 3;
    int b = bh >> 4, h = bh & 15;
    const unsigned short* Abase = vT  + (size_t)(h * 64) * 16384 + b * 2048 + sp * 512;
    const unsigned short* Bbase = kpT + (size_t)(h * 64) * 16384 + b * 2048 + sp * 512;
    __shared__ unsigned short Al[64 * 64];
    __shared__ unsigned short Bl[64 * 64];
    int t = threadIdx.x;
    int lane = t & 63, wid = t >> 6;
    int l15 = lane & 15, l4 = lane >> 4;
    int wr = wid >> 1, wc = wid & 1;
    f32x4 acc[2][2] = {};
    float ks0 = 0.f, ks1 = 0.f;   // partial row-sums for rows t>>3 and 32+(t>>3)
    for (int k0 = 0; k0 < 512; k0 += 64) {
        #pragma unroll
        for (int i = 0; i < 2; i++) {
            int chunk = i * 256 + t;
            int row = chunk >> 3, c = (chunk & 7) * 8;
            u16x8 av = *(const u16x8*)(Abase + (size_t)row * 16384 + k0 + c);
            u16x8 bv = *(const u16x8*)(Bbase + (size_t)row * 16384 + k0 + c);
            float s = 0.f;
            #pragma unroll
            for (int q = 0; q < 8; q++) s += bf2f(bv[q]);
            if (i == 0) ks0 += s; else ks1 += s;
            int off = (row * 128 + c * 2) ^ ((row & 7) << 4);
            *(u16x8*)((char*)Al + off) = av;
            *(u16x8*)((char*)Bl + off) = bv;
        }
        __syncthreads();
        #pragma unroll
        for (int kh = 0; kh < 2; kh++) {
            bf16x8 af[2], bf[2];
            #pragma unroll
            for (int mi = 0; mi < 2; mi++) {
                int row = wr * 32 + mi * 16 + l15;
                int off = (row * 128 + (kh * 32 + l4 * 8) * 2) ^ ((row & 7) << 4);
                af[mi] = *(const bf16x8*)((const char*)Al + off);
            }
            #pragma unroll
            for (int ni = 0; ni < 2; ni++) {
                int row = wc * 32 + ni * 16 + l15;
                int off = (row * 128 + (kh * 32 + l4 * 8) * 2) ^ ((row & 7) << 4);
                bf[ni] = *(const bf16x8*)((const char*)Bl + off);
            }
            #pragma unroll
            for (int mi = 0; mi < 2; mi++)
                #pragma unroll
                for (int ni = 0; ni < 2; ni++)
                    acc[mi][ni] = __builtin_amdgcn_mfma_f32_16x16x32_bf16(af[mi], bf[ni], acc[mi][ni], 0, 0, 0);
        }
        __syncthreads();
    }
    // ksum reduce: rows t>>3 (ks0) and 32+(t>>3) (ks1), 8 consecutive lanes/row
    #pragma unroll
    for (int o = 4; o > 0; o >>= 1) { ks0 += __shfl_down(ks0, o); ks1 += __shfl_down(ks1, o); }
    if ((t & 7) == 0) {
        atomicAdd(&ksum[bh * 64 + (t >> 3)], ks0);
        atomicAdd(&ksum[bh * 64 + 32 + (t >> 3)], ks1);
    }
    float* pb = pbuf + ((size_t)sp * 128 + bh) * 4096;
    #pragma unroll
    for (int mi = 0; mi < 2; mi++)
        #pragma unroll
        for (int ni = 0; ni < 2; ni++)
            #pragma unroll
            for (int j = 0; j < 4; j++) {
                int d = wr * 32 + mi * 16 + l4 * 4 + j;
                int m = wc * 32 + ni * 16 + l15;
                pb[d * 64 + m] = acc[mi][ni][j];
            }
}

// ---------------------------------------------------------------------------
// LayerNorm fp32 [rows][1024] -> bf16, gamma/beta applied
// ---------------------------------------------------------------------------
__global__ __launch_bounds__(256) void ln_kernel(
    const float* __restrict__ x, const float* __restrict__ gamma,
    const float* __restrict__ beta, unsigned short* __restrict__ out)
{
    int row = blockIdx.x;
    int t = threadIdx.x;
    float4 v = ((const float4*)(x + (size_t)row * 1024))[t];
    float s  = v.x + v.y + v.z + v.w;
    float s2 = v.x * v.x + v.y * v.y + v.z * v.z + v.w * v.w;
    #pragma unroll
    for (int o = 32; o > 0; o >>= 1) { s += __shfl_down(s, o); s2 += __shfl_down(s2, o); }
    __shared__ float red[8];
    if ((t & 63) == 0) { red[t >> 6] = s; red[4 + (t >> 6)] = s2; }
    __syncthreads();
    s  = red[0] + red[1] + red[2] + red[3];
    s2 = red[4] + red[5] + red[6] + red[7];
    float mu  = s * (1.0f / 1024.0f);
    float var = s2 * (1.0f / 1024.0f) - mu * mu;
    float rs  = rsqrtf(var + 1e-6f);
    float4 g  = ((const float4*)gamma)[t];
    float4 be = ((const float4*)beta)[t];
    u16x4 o4;
    o4[0] = f2bf((v.x - mu) * rs * g.x + be.x);
    o4[1] = f2bf((v.y - mu) * rs * g.y + be.y);
    o4[2] = f2bf((v.z - mu) * rs * g.z + be.z);
    o4[3] = f2bf((v.w - mu) * rs * g.w + be.w);
    *(u16x4*)(out + (size_t)row * 1024 + t * 4) = o4;
}

// ---------------------------------------------------------------------------
// LayerNorm bf16 [rows][1024] -> bf16
// ---------------------------------------------------------------------------
__global__ __launch_bounds__(256) void ln_bf16_kernel(
    const unsigned short* __restrict__ x, const float* __restrict__ gamma,
    const float* __restrict__ beta, unsigned short* __restrict__ out)
{
    int row = blockIdx.x;
    int t = threadIdx.x;
    u16x4 uv = ((const u16x4*)(x + (size_t)row * 1024))[t];
    float v0 = bf2f(uv[0]), v1 = bf2f(uv[1]), v2 = bf2f(uv[2]), v3 = bf2f(uv[3]);
    float s  = v0 + v1 + v2 + v3;
    float s2 = v0 * v0 + v1 * v1 + v2 * v2 + v3 * v3;
    #pragma unroll
    for (int o = 32; o > 0; o >>= 1) { s += __shfl_down(s, o); s2 += __shfl_down(s2, o); }
    __shared__ float red[8];
    if ((t & 63) == 0) { red[t >> 6] = s; red[4 + (t >> 6)] = s2; }
    __syncthreads();
    s  = red[0] + red[1] + red[2] + red[3];
    s2 = red[4] + red[5] + red[6] + red[7];
    float mu  = s * (1.0f / 1024.0f);
    float var = s2 * (1.0f / 1024.0f) - mu * mu;
    float rs  = rsqrtf(var + 1e-6f);
    float4 g  = ((const float4*)gamma)[t];
    float4 be = ((const float4*)beta)[t];
    u16x4 o4;
    o4[0] = f2bf((v0 - mu) * rs * g.x + be.x);
    o4[1] = f2bf((v1 - mu) * rs * g.y + be.y);
    o4[2] = f2bf((v2 - mu) * rs * g.z + be.z);
    o4[3] = f2bf((v3 - mu) * rs * g.w + be.w);
    *(u16x4*)(out + (size_t)row * 1024 + t * 4) = o4;
}

// ---------------------------------------------------------------------------
// GEMM 256x256, BK=64, 8 waves (2Mx4N) — round-12/14 proven structure.
// Double-buffered LDS; gload_lds staging (pre-swizzled source + swizzled
// ds_read, 0 conflicts); ONE barrier + ONE covered vmcnt(0) per K-tile;
// LDS-repack bf16 epilogue (full-line stores).
// EP: 0 = bf16 | 1 = relu+1e-3 bf16 | 5 = row-cond relu (tm<4) bf16
//     2 = +addv(f32) -> bf16 | 3 = +bias, gelu, bf16
//     4 = +bias, gelu, +addv(bf16) -> f32
// Requires M%256==0, N%256==0, K%128==0, grid%8==0.
// ---------------------------------------------------------------------------
template <int EP>
__global__ __launch_bounds__(512) void gemm256(
    const unsigned short* __restrict__ A, const unsigned short* __restrict__ Bt,
    void* __restrict__ C, const float* __restrict__ bias,
    const void* __restrict__ addv, int M, int N, int K)
{
    __shared__ unsigned short ldsbuf[69632];
    const int nbn = N >> 8;
    const int nwg = (M >> 8) * nbn;
    int bid = blockIdx.x;
    int wg = (bid & 7) * (nwg >> 3) + (bid >> 3);    // XCD swizzle (nwg%8==0)
    int tm = wg / nbn, tn = wg % nbn;
    const int tid = threadIdx.x;
    const int lane = tid & 63;
    const int l15 = lane & 15, l4 = lane >> 4;
    const int wid = tid >> 6;
    const int wr = wid >> 2, wc = wid & 3;           // 2 x 4 wave grid

    const unsigned short* Ab = A + (size_t)(tm << 8) * K;
    const unsigned short* Bb = Bt + (size_t)(tn << 8) * K;

    const int swz   = (l15 & 7) << 4;
    const int koff0 = (l4 * 16) ^ swz;
    const int koff1 = (64 + l4 * 16) ^ swz;
    const int arow  = wr * 16384 + l15 * 128;
    const int brow  = wc * 8192  + l15 * 128;

    int goff[4];
    #pragma unroll
    for (int i = 0; i < 4; i++) {
        int cid = i * 512 + tid;
        int row = cid >> 3, c = cid & 7;
        goff[i] = row * K + ((c ^ (row & 7)) << 3);
    }
    const int ld0 = tid * 8;

    f32x4 acc[8][4] = {};
    const int NT = K >> 6;

#define STAGE_TILE(kt, slot)                                                   \
    {                                                                          \
        int k0_ = (kt) << 6;                                                   \
        _Pragma("unroll")                                                      \
        for (int i_ = 0; i_ < 4; i_++) {                                       \
            gload_lds16(Ab + (size_t)(goff[i_] + k0_), ldsbuf + (slot) * 32768 + ld0 + i_ * 4096); \
            gload_lds16(Bb + (size_t)(goff[i_] + k0_), ldsbuf + (slot) * 32768 + 16384 + ld0 + i_ * 4096); \
        }                                                                      \
    }

#define TILE_STEP(t_, s_)                                                      \
    {                                                                          \
        if ((t_) + 1 < NT) STAGE_TILE((t_) + 1, (s_) ^ 1);                     \
        const char* As_ = (const char*)(ldsbuf + (s_) * 32768);                \
        const char* Bs_ = (const char*)(ldsbuf + (s_) * 32768 + 16384);        \
        bf16x8 a_[8], b_[4];                                                   \
        _Pragma("unroll")                                                      \
        for (int m = 0; m < 8; m++) a_[m] = *(const bf16x8*)(As_ + arow + m * 2048 + koff0); \
        _Pragma("unroll")                                                      \
        for (int n = 0; n < 4; n++) b_[n] = *(const bf16x8*)(Bs_ + brow + n * 2048 + koff0); \
        __builtin_amdgcn_s_setprio(1);                                         \
        _Pragma("unroll")                                                      \
        for (int m = 0; m < 8; m++)                                            \
            _Pragma("unroll")                                                  \
            for (int n = 0; n < 4; n++)                                        \
                acc[m][n] = __builtin_amdgcn_mfma_f32_16x16x32_bf16(a_[m], b_[n], acc[m][n], 0, 0, 0); \
        __builtin_amdgcn_s_setprio(0);                                         \
        _Pragma("unroll")                                                      \
        for (int m = 0; m < 8; m++) a_[m] = *(const bf16x8*)(As_ + arow + m * 2048 + koff1); \
        _Pragma("unroll")                                                      \
        for (int n = 0; n < 4; n++) b_[n] = *(const bf16x8*)(Bs_ + brow + n * 2048 + koff1); \
        __builtin_amdgcn_s_setprio(1);                                         \
        _Pragma("unroll")                                                      \
        for (int m = 0; m < 8; m++)                                            \
            _Pragma("unroll")                                                  \
            for (int n = 0; n < 4; n++)                                        \
                acc[m][n] = __builtin_amdgcn_mfma_f32_16x16x32_bf16(a_[m], b_[n], acc[m][n], 0, 0, 0); \
        __builtin_amdgcn_s_setprio(0);                                         \
        asm volatile("s_waitcnt vmcnt(0)" ::: "memory");                       \
        __builtin_amdgcn_s_barrier();                                          \
    }

    STAGE_TILE(0, 0);
    asm volatile("s_waitcnt vmcnt(0)" ::: "memory");
    __builtin_amdgcn_s_barrier();

    for (int t = 0; t < NT; t += 2) {
        TILE_STEP(t, 0);
        TILE_STEP(t + 1, 1);
    }
#undef TILE_STEP
#undef STAGE_TILE

    int rbase = (tm << 8) + wr * 128;
    int cbase = (tn << 8) + wc * 64;
    if constexpr (EP == 4) {
        // fp32 out = gelu(val+bias) + bf16 addv; 16 lanes x 4B fill 64B lines
        const unsigned short* av16 = (const unsigned short*)addv;
        #pragma unroll
        for (int n = 0; n < 4; n++) {
            int col = cbase + n * 16 + l15;
            float bval = bias[col];
            #pragma unroll
            for (int mf = 0; mf < 8; mf++) {
                #pragma unroll
                for (int j = 0; j < 4; j++) {
                    int row = rbase + mf * 16 + l4 * 4 + j;
                    float val = gelu_fast(acc[mf][n][j] + bval);
                    ((float*)C)[(size_t)row * N + col] = val + bf2f(av16[(size_t)row * N + col]);
                }
            }
        }
    } else {
        // bf16 outputs: repack via wave-private LDS (stride 68) -> full lines
        const float* avf = (const float*)addv;
        unsigned short* myl = ldsbuf + wid * 8704;
        #pragma unroll
        for (int n = 0; n < 4; n++) {
            int col = cbase + n * 16 + l15;
            float bval = 0.f;
            if constexpr (EP == 3) bval = bias[col];
            #pragma unroll
            for (int mf = 0; mf < 8; mf++) {
                #pragma unroll
                for (int j = 0; j < 4; j++) {
                    int row = rbase + mf * 16 + l4 * 4 + j;
                    float val = acc[mf][n][j];
                    if constexpr (EP == 1) val = fmaxf(val, 0.f) + 1e-3f;
                    if constexpr (EP == 5) { if (tm < 4) val = fmaxf(val, 0.f) + 1e-3f; }
                    if constexpr (EP == 3) val = gelu_fast(val + bval);
                    if constexpr (EP == 2) val += avf[(size_t)row * N + col];
                    myl[(mf * 16 + l4 * 4 + j) * 68 + n * 16 + l15] = f2bf(val);
                }
            }
        }
        #pragma unroll
        for (int c = 0; c < 16; c++) {
            int lrow = c * 8 + (lane >> 3);
            int cc = (lane & 7) * 8;
            u16x4 lo = *(const u16x4*)(myl + lrow * 68 + cc);
            u16x4 hi = *(const u16x4*)(myl + lrow * 68 + cc + 4);
            unsigned short* dst = (unsigned short*)C + (size_t)(rbase + lrow) * N + cbase + cc;
            *(u16x4*)dst = lo;
            *(u16x4*)(dst + 4) = hi;
        }
    }
}

// ---------------------------------------------------------------------------
// att = (qp @ sum_sp pbuf) / (qp @ ksum), per (b,h), 128-row tiles, in place
// over qp. reduce4 fused into the Bl staging.
// ---------------------------------------------------------------------------
__global__ __launch_bounds__(256) void att_num_kernel(
    const unsigned short* __restrict__ qp, const float* __restrict__ pbuf,
    const float* __restrict__ ksum, unsigned short* __restrict__ att)
{
    int blk = blockIdx.x;
    int t16 = blk & 15, h = (blk >> 4) & 15, b = blk >> 8;
    int bh = b * 16 + h;
    __shared__ unsigned short Al[128 * 64];
    __shared__ unsigned short Bl[64 * 64];
    __shared__ float kss[64];
    int tid = threadIdx.x;
    int lane = tid & 63, wid = tid >> 6;
    int l15 = lane & 15, l4 = lane >> 4;
    const unsigned short* Ab = qp + ((size_t)(b * 2048 + t16 * 128)) * 1024 + h * 64;
    const float* Bb  = pbuf + (size_t)bh * 4096;
    const float* ksb = ksum + bh * 64;
    #pragma unroll
    for (int i = 0; i < 4; i++) {
        int chunk = tid + i * 256;
        int row = chunk >> 3, c = (chunk & 7) * 8;
        u16x8 av = *(const u16x8*)(Ab + (size_t)row * 1024 + c);
        int off = (row * 128 + c * 2) ^ ((row & 7) << 4);
        *(u16x8*)((char*)Al + off) = av;
    }
    #pragma unroll
    for (int i = 0; i < 2; i++) {
        int chunk = tid + i * 256;
        int row = chunk >> 3, c = (chunk & 7) * 8;
        float sum8[8] = {};
        #pragma unroll
        for (int sp = 0; sp < 4; sp++) {
            const float* src = Bb + (size_t)sp * 524288 + row * 64 + c;
            #pragma unroll
            for (int q = 0; q < 8; q++) sum8[q] += src[q];
        }
        u16x8 bv;
        #pragma unroll
        for (int q = 0; q < 8; q++) bv[q] = f2bf(sum8[q]);
        int off = (row * 128 + c * 2) ^ ((row & 7) << 4);
        *(u16x8*)((char*)Bl + off) = bv;
    }
    if (tid < 64) kss[tid] = ksb[tid];
    __syncthreads();

    f32x4 acc[2][4] = {};
    #pragma unroll
    for (int kk = 0; kk < 64; kk += 32) {
        bf16x8 af[2], bfr[4];
        #pragma unroll
        for (int m = 0; m < 2; m++) {
            int row = wid * 32 + m * 16 + l15;
            int off = (row * 128 + (kk + l4 * 8) * 2) ^ ((row & 7) << 4);
            af[m] = *(const bf16x8*)((const char*)Al + off);
        }
        #pragma unroll
        for (int n = 0; n < 4; n++) {
            int row = n * 16 + l15;
            int off = (row * 128 + (kk + l4 * 8) * 2) ^ ((row & 7) << 4);
            bfr[n] = *(const bf16x8*)((const char*)Bl + off);
        }
        #pragma unroll
        for (int m = 0; m < 2; m++)
            #pragma unroll
            for (int n = 0; n < 4; n++)
                acc[m][n] = __builtin_amdgcn_mfma_f32_16x16x32_bf16(af[m], bfr[n], acc[m][n], 0, 0, 0);
    }
    __syncthreads();  // everyone done reading Al before in-place writes land

    #pragma unroll
    for (int m = 0; m < 2; m++) {
        #pragma unroll
        for (int j = 0; j < 4; j++) {
            int lrow = wid * 32 + m * 16 + l4 * 4 + j;
            float den = 0.f;
            #pragma unroll
            for (int mm = 0; mm < 64; mm += 8) {
                int off = (lrow * 128 + mm * 2) ^ ((lrow & 7) << 4);
                u16x8 a8 = *(const u16x8*)((const char*)Al + off);
                #pragma unroll
                for (int q = 0; q < 8; q++) den += bf2f(a8[q]) * kss[mm + q];
            }
            float rden = 1.0f / den;
            size_t grow = (size_t)(b * 2048 + t16 * 128 + lrow);
            #pragma unroll
            for (int n = 0; n < 4; n++) {
                int col = h * 64 + n * 16 + l15;
                att[grow * 1024 + col] = f2bf(acc[m][n][j] * rden);
            }
        }
    }
}

// ---------------------------------------------------------------------------
extern "C" void kernel_launch(void* const* d_in, const int* in_sizes, int n_in,
                              void* d_out, int out_size, void* d_ws, size_t ws_size,
                              hipStream_t stream) {
    (void)in_sizes; (void)n_in; (void)out_size; (void)ws_size;
    const float* x      = (const float*)d_in[0];
    const float* gamma1 = (const float*)d_in[1];
    const float* beta1  = (const float*)d_in[2];
    const float* wq     = (const float*)d_in[3];
    const float* wk     = (const float*)d_in[4];
    const float* wv     = (const float*)d_in[5];
    const float* wo     = (const float*)d_in[6];
    const float* w1     = (const float*)d_in[7];
    const float* b1     = (const float*)d_in[8];
    const float* w2     = (const float*)d_in[9];
    const float* b2     = (const float*)d_in[10];
    float* out = (float*)d_out;

    const size_t MB = 1024 * 1024;
    char* ws = (char*)d_ws;
    unsigned short* wq_bt = (unsigned short*)(ws + 0 * MB);
    unsigned short* wk_bt = (unsigned short*)(ws + 2 * MB);   // wk_bt+wv_bt contiguous (4 MB)
    unsigned short* wv_bt = (unsigned short*)(ws + 4 * MB);
    unsigned short* wo_bt = (unsigned short*)(ws + 6 * MB);
    unsigned short* w1_bt = (unsigned short*)(ws + 8 * MB);
    unsigned short* w2_bt = (unsigned short*)(ws + 16 * MB);
    unsigned short* lnbuf = (unsigned short*)(ws + 24 * MB);   // 32 MB (ln1 then ln2)
    unsigned short* add1b = (unsigned short*)(ws + 56 * MB);   // 32 MB bf16 residual
    float*          pbuf  = (float*)(ws + 88 * MB);            // 8 MB partials
    unsigned short* qp    = (unsigned short*)(ws + 120 * MB);  // 32 MB (att in-place later)
    unsigned short* kpT   = (unsigned short*)(ws + 152 * MB);  // 32 MB [1024 feat][16384 l]
    unsigned short* vT    = (unsigned short*)(ws + 184 * MB);  // 32 MB (contiguous after kpT)
    float*          ksum  = (float*)(ws + 218 * MB);           // 32 KB
    unsigned short* hbuf  = (unsigned short*)(ws + 120 * MB);  // 128 MB, reuses qp..region

    dim3 blk(256), blk512(512);
    // weights -> bf16 transposed [N][K]
    transpose_w<<<dim3(256),  blk, 0, stream>>>(wq, wq_bt, 1024, 1024);
    transpose_w<<<dim3(256),  blk, 0, stream>>>(wk, wk_bt, 1024, 1024);
    transpose_w<<<dim3(256),  blk, 0, stream>>>(wv, wv_bt, 1024, 1024);
    transpose_w<<<dim3(256),  blk, 0, stream>>>(wo, wo_bt, 1024, 1024);
    transpose_w<<<dim3(1024), blk, 0, stream>>>(w1, w1_bt, 1024, 4096);
    transpose_w<<<dim3(1024), blk, 0, stream>>>(w2, w2_bt, 4096, 1024);
    // ln1
    ln_kernel<<<dim3(16384), blk, 0, stream>>>(x, gamma1, beta1, lnbuf);
    // Q row-major; K+V fused output-transposed (A = [wk_bt;wv_bt], M=2048):
    // rows 0-1023 -> kpT (relu+stab via EP5 tm<4), rows 1024-2047 -> vT
    gemm256<1><<<dim3(256), blk512, 0, stream>>>(lnbuf, wq_bt, qp, nullptr, nullptr, 16384, 1024, 1024);
    gemm256<5><<<dim3(512), blk512, 0, stream>>>(wk_bt, lnbuf, kpT, nullptr, nullptr, 2048, 16384, 1024);
    // kvs (split-K MFMA, fused ksum)
    hipMemsetAsync(ksum, 0, 32 * 1024, stream);
    kvs_mfma<<<dim3(512), blk, 0, stream>>>(vT, kpT, pbuf, ksum);
    // att = (qp@kvs)/(qp@ksum), in place over qp (reduce4 fused)
    att_num_kernel<<<dim3(2048), blk, 0, stream>>>(qp, pbuf, ksum, qp);
    // attn_out = att @ wo, + x -> add1 (bf16)
    gemm256<2><<<dim3(256), blk512, 0, stream>>>(qp, wo_bt, add1b, nullptr, x, 16384, 1024, 1024);
    // ln2 on bf16 residual
    ln_bf16_kernel<<<dim3(16384), blk, 0, stream>>>(add1b, gamma1, beta1, lnbuf);
    // FFN
    gemm256<3><<<dim3(1024), blk512, 0, stream>>>(lnbuf, w1_bt, hbuf, b1, nullptr, 16384, 4096, 1024);
    gemm256<4><<<dim3(256),  blk512, 0, stream>>>(hbuf, w2_bt, out, b2, add1b, 16384, 1024, 4096);
}